// Round 5
// baseline (367.184 us; speedup 1.0000x reference)
//
#include <hip/hip_runtime.h>

typedef _Float16 half8 __attribute__((ext_vector_type(8)));
typedef _Float16 half4 __attribute__((ext_vector_type(4)));
typedef float f32x4 __attribute__((ext_vector_type(4)));

#define TT 512
#define HH 64
#define MB 4      // batches per block -> 512 blocks -> 2 blocks/CU
#define S  104    // state row stride (f16): [h(64)|x(4)|1|zeros|pad]
#define GS 72     // gbuf batch stride (dwords): 16B-aligned rows, padded banks

__device__ __forceinline__ float sigm(float x) {
    return __builtin_amdgcn_rcpf(1.f + __builtin_amdgcn_exp2f(-1.4426950408889634f * x));
}
__device__ __forceinline__ float tanh_f(float x) {
    return 1.f - 2.f * __builtin_amdgcn_rcpf(1.f + __builtin_amdgcn_exp2f(2.8853900817779268f * x));
}

__global__ __launch_bounds__(256, 2)
void lstm_v5(const float* __restrict__ x,
             const float* __restrict__ W_ih,
             const float* __restrict__ W_hh,
             const float* __restrict__ b_ih,
             const float* __restrict__ b_hh,
             const float* __restrict__ W_fc,
             const float* __restrict__ b_fc,
             float* __restrict__ out)
{
    __shared__ __align__(16) _Float16 st[2][MB * S];   // 1664 B: 4 real state rows, dbuf
    __shared__ __align__(16) _Float16 xch[MB * 64 * 4];// 2048 B: 64-step x chunk
    __shared__ __align__(16) float gbuf[4 * MB * GS];  // 4608 B: per-wave gate routing

    const int tid = threadIdx.x;
    const int w   = tid >> 6;      // wave 0..3
    const int l   = tid & 63;
    const int q   = l >> 4;
    const int col = l & 15;
    const int b0  = blockIdx.x * MB;
    const bool real = (col < MB);  // cols 0..3 = real batches

    // ---- persistent A fragments (weights), 4 tiles per wave ----
    // tile p of wave w: rows r(m) = 64*(m&3) + 16w + 4p + (m>>2)
    // => lane (q,col) reg j = gate j of unit u = 16w + 4p + q, batch col
    half8 aw[4][3];
    #pragma unroll
    for (int p = 0; p < 4; ++p) {
        const int r = 64 * (col & 3) + 16 * w + 4 * p + (col >> 2);
        #pragma unroll
        for (int c = 0; c < 2; ++c) {
            const float* src = W_hh + r * HH + 32 * c + 8 * q;
            half8 v;
            #pragma unroll
            for (int j = 0; j < 8; ++j) v[j] = (_Float16)src[j];
            aw[p][c] = v;
        }
        half8 v = {};
        if (q == 0) {   // k=64..67 -> W_ih, k=68 -> bias
            #pragma unroll
            for (int j = 0; j < 4; ++j) v[j] = (_Float16)W_ih[r * 4 + j];
            v[4] = (_Float16)(b_ih[r] + b_hh[r]);
        }
        aw[p][2] = v;
    }

    // ---- init: zero state, first x chunk, '1' slots, x_0 ----
    {
        _Float16* p0 = &st[0][0];
        for (int i = tid; i < 2 * MB * S; i += 256) p0[i] = (_Float16)0.f;
    }
    float4 xpre;   // prefetch register: one float4 per thread = (b=tid>>6, tt=tid&63)
    {
        const int b = tid >> 6, tt = tid & 63;
        xpre = *(const float4*)(x + ((size_t)(b0 + b) * TT + tt) * 4);   // chunk 0
        _Float16* d = &xch[b * 256 + tt * 4];
        half4 hx;
        hx[0] = (_Float16)xpre.x; hx[1] = (_Float16)xpre.y;
        hx[2] = (_Float16)xpre.z; hx[3] = (_Float16)xpre.w;
        *(half4*)d = hx;
        xpre = *(const float4*)(x + ((size_t)(b0 + b) * TT + 64 + tt) * 4); // chunk 1
    }
    __syncthreads();
    if (tid < 2 * MB) st[tid >> 2][(tid & 3) * S + 68] = (_Float16)1.0f;   // bias '1'
    if (tid < MB)     *(half4*)&st[0][tid * S + 64] = *(const half4*)&xch[tid * 256];
    __syncthreads();

    float cst = 0.f;   // one real cell per lane: batch col&3, unit 16w+4*(col>>2)+q

    #pragma unroll 2
    for (int t = 0; t < TT; ++t) {
        const int rb = t & 1, wb = rb ^ 1;

        if ((t & 63) == 0 && t > 0) {
            // commit prefetched chunk to LDS; prefetch next
            const int b = tid >> 6, tt = tid & 63;
            half4 hx;
            hx[0] = (_Float16)xpre.x; hx[1] = (_Float16)xpre.y;
            hx[2] = (_Float16)xpre.z; hx[3] = (_Float16)xpre.w;
            *(half4*)&xch[b * 256 + tt * 4] = hx;
            int c = (t >> 6) + 1; if (c > 7) c = 7;
            xpre = *(const float4*)(x + ((size_t)(b0 + b) * TT + c * 64 + tt) * 4);
            __syncthreads();
        }

        const _Float16* sr = &st[rb][0];
        const half8 z8 = {};
        half8 bh0 = real ? *(const half8*)&sr[col * S +      8 * q] : z8;  // k 0..31
        half8 bh1 = real ? *(const half8*)&sr[col * S + 32 + 8 * q] : z8;  // k 32..63
        half8 bx  = real ? *(const half8*)&sr[col * S + 64 + 8 * q] : z8;  // k 64..95

        // stage x_{t+1} into write buffer
        if (((t + 1) & 63) != 0) {
            if (tid < MB)
                *(half4*)&st[wb][tid * S + 64] =
                    *(const half4*)&xch[tid * 256 + ((t + 1) & 63) * 4];
        } else {
            // chunk boundary: x_{t+1} comes from the prefetch register (tt==0 threads)
            if ((tid & 63) == 0) {
                half4 hx;
                hx[0] = (_Float16)xpre.x; hx[1] = (_Float16)xpre.y;
                hx[2] = (_Float16)xpre.z; hx[3] = (_Float16)xpre.w;
                *(half4*)&st[wb][(tid >> 6) * S + 64] = hx;
            }
        }

        // 4 tiles, 3 chained MFMAs each (tiles independent -> ILP)
        const f32x4 z = {0.f, 0.f, 0.f, 0.f};
        f32x4 acc[4];
        #pragma unroll
        for (int p = 0; p < 4; ++p) {
            f32x4 a = __builtin_amdgcn_mfma_f32_16x16x32_f16(aw[p][0], bh0, z, 0, 0, 0);
            a = __builtin_amdgcn_mfma_f32_16x16x32_f16(aw[p][1], bh1, a, 0, 0, 0);
            a = __builtin_amdgcn_mfma_f32_16x16x32_f16(aw[p][2], bx,  a, 0, 0, 0);
            acc[p] = a;
        }

        // route real gates so every lane owns exactly 1 real cell (wave-internal LDS)
        if (real) {
            float* g = &gbuf[(w * MB + col) * GS];
            #pragma unroll
            for (int p = 0; p < 4; ++p)
                *(f32x4*)&g[(4 * p + q) * 4] = acc[p];
        }
        const f32x4 gates =
            *(const f32x4*)&gbuf[(w * MB + (col & 3)) * GS + (4 * (col >> 2) + q) * 4];

        // cell update: batch b = col&3, unit u = 16w + 4*(col>>2) + q
        {
            const float gi = gates[0], gf = gates[1], gg = gates[2], go = gates[3];
            float c2 = sigm(gf) * cst + sigm(gi) * tanh_f(gg);
            cst = c2;
            const float hn = sigm(go) * tanh_f(c2);
            st[wb][(col & 3) * S + 16 * w + 4 * (col >> 2) + q] = (_Float16)hn;
        }
        __syncthreads();
    }

    // ---- FC epilogue: final h in st[0] rows 0..3 (TT even) ----
    if (tid < MB * 4) {
        const int b = tid >> 2, o = tid & 3;
        float s = b_fc[o];
        const float* wf = W_fc + o * HH;
        #pragma unroll
        for (int k = 0; k < HH; ++k)
            s = fmaf((float)st[0][b * S + k], wf[k], s);
        out[(size_t)(b0 + b) * 4 + o] = s;
    }
}

extern "C" void kernel_launch(void* const* d_in, const int* in_sizes, int n_in,
                              void* d_out, int out_size, void* d_ws, size_t ws_size,
                              hipStream_t stream) {
    const float* x    = (const float*)d_in[0];
    const float* W_ih = (const float*)d_in[1];
    const float* W_hh = (const float*)d_in[2];
    const float* b_ih = (const float*)d_in[3];
    const float* b_hh = (const float*)d_in[4];
    const float* W_fc = (const float*)d_in[5];
    const float* b_fc = (const float*)d_in[6];
    float* out = (float*)d_out;
    lstm_v5<<<2048 / MB, 256, 0, stream>>>(x, W_ih, W_hh, b_ih, b_hh, W_fc, b_fc, out);
}

// Round 6
// 333.741 us; speedup vs baseline: 1.1002x; 1.1002x over previous
//
#include <hip/hip_runtime.h>

typedef _Float16 half8 __attribute__((ext_vector_type(8)));
typedef _Float16 half4 __attribute__((ext_vector_type(4)));
typedef _Float16 half2v __attribute__((ext_vector_type(2)));
typedef float f32x4 __attribute__((ext_vector_type(4)));

#define TT 512
#define HH 64
#define MB 8      // real batches per block -> 256 blocks (cols 8..15 garbage-contained)
#define S  104    // state row stride (f16): [h(64)|x(4)|1|zeros|pad]

__device__ __forceinline__ float sigm(float x) {
    return __builtin_amdgcn_rcpf(1.f + __builtin_amdgcn_exp2f(-1.4426950408889634f * x));
}
__device__ __forceinline__ float tanh_f(float x) {
    return 1.f - 2.f * __builtin_amdgcn_rcpf(1.f + __builtin_amdgcn_exp2f(2.8853900817779268f * x));
}

__global__ __launch_bounds__(512, 1)
void lstm_v6(const float* __restrict__ x,
             const float* __restrict__ W_ih,
             const float* __restrict__ W_hh,
             const float* __restrict__ b_ih,
             const float* __restrict__ b_hh,
             const float* __restrict__ W_fc,
             const float* __restrict__ b_fc,
             float* __restrict__ out)
{
    __shared__ __align__(16) _Float16 st[2][16 * S];       // state, double-buffered
    __shared__ __align__(16) _Float16 xch[2][MB * 64 * 4]; // x chunks, double-buffered

    const int tid = threadIdx.x;
    const int w   = tid >> 6;      // wave 0..7
    const int l   = tid & 63;
    const int q   = l >> 4;
    const int col = l & 15;
    const int b0  = blockIdx.x * MB;

    // ---- persistent A fragments (weights), 2 tiles per wave ----
    // tile p of wave w covers gate-rows r(m) = 64*(m&3) + 8w + 2*(m>>2) + p
    // => lane (q,col) reg j = gate j of unit u = 8w + 2q + p
    half8 aw[2][3];
    #pragma unroll
    for (int p = 0; p < 2; ++p) {
        const int r = 64 * (col & 3) + 8 * w + 2 * (col >> 2) + p;
        #pragma unroll
        for (int c = 0; c < 2; ++c) {
            const float* src = W_hh + r * HH + 32 * c + 8 * q;
            half8 v;
            #pragma unroll
            for (int j = 0; j < 8; ++j) v[j] = (_Float16)src[j];
            aw[p][c] = v;
        }
        half8 v = {};
        if (q == 0) {   // k=64..67 -> W_ih, k=68 -> bias
            #pragma unroll
            for (int j = 0; j < 4; ++j) v[j] = (_Float16)W_ih[r * 4 + j];
            v[4] = (_Float16)(b_ih[r] + b_hh[r]);
        }
        aw[p][2] = v;
    }

    // ---- init: zero state; x chunk 0 -> xch[0]; prefetch chunk 1 into regs ----
    {
        _Float16* p0 = &st[0][0];
        for (int i = tid; i < 2 * 16 * S; i += 512) p0[i] = (_Float16)0.f;
    }
    const int xb = tid >> 6, xt = tid & 63;              // thread -> (batch, step-in-chunk)
    const float* xbase = x + (size_t)(b0 + xb) * TT * 4;
    float4 xpre = *(const float4*)(xbase + xt * 4);      // chunk 0
    {
        half4 hx;
        hx[0] = (_Float16)xpre.x; hx[1] = (_Float16)xpre.y;
        hx[2] = (_Float16)xpre.z; hx[3] = (_Float16)xpre.w;
        *(half4*)&xch[0][xb * 256 + xt * 4] = hx;
    }
    xpre = *(const float4*)(xbase + (64 + xt) * 4);      // chunk 1 -> regs
    __syncthreads();
    if (tid < 32) st[tid >> 4][(tid & 15) * S + 68] = (_Float16)1.0f;  // bias '1'
    if (tid < MB) *(half4*)&st[0][tid * S + 64] = *(const half4*)&xch[0][tid * 256];
    __syncthreads();

    float cst[2] = {0.f, 0.f};

    #pragma unroll 2
    for (int t = 0; t < TT; ++t) {
        const int rb = t & 1, wb = rb ^ 1;

        if ((t & 63) == 0) {
            // commit prefetched chunk c+1 to xch[(c+1)&1]; prefetch chunk c+2.
            // No extra barrier: first consumer is 63 step-barriers away.
            const int c = t >> 6;
            half4 hx;
            hx[0] = (_Float16)xpre.x; hx[1] = (_Float16)xpre.y;
            hx[2] = (_Float16)xpre.z; hx[3] = (_Float16)xpre.w;
            *(half4*)&xch[(c + 1) & 1][xb * 256 + xt * 4] = hx;
            int cn = c + 2; if (cn > 7) cn = 7;
            xpre = *(const float4*)(xbase + (cn * 64 + xt) * 4);
        }

        const _Float16* sr = &st[rb][0];
        half8 bh0 = *(const half8*)&sr[col * S +      8 * q];   // k 0..31
        half8 bh1 = *(const half8*)&sr[col * S + 32 + 8 * q];   // k 32..63
        half8 bx  = *(const half8*)&sr[col * S + 64];           // broadcast; q>0 -> A=0

        // stage x_{t+1} into write buffer (pure LDS; 8 threads)
        if (tid < MB) {
            const int tn = t + 1;
            *(half4*)&st[wb][tid * S + 64] =
                *(const half4*)&xch[(tn >> 6) & 1][tid * 256 + (tn & 63) * 4];
        }

        // 6 independent MFMAs, tree-add
        const f32x4 z = {0.f, 0.f, 0.f, 0.f};
        f32x4 t00 = __builtin_amdgcn_mfma_f32_16x16x32_f16(aw[0][0], bh0, z, 0, 0, 0);
        f32x4 t01 = __builtin_amdgcn_mfma_f32_16x16x32_f16(aw[0][1], bh1, z, 0, 0, 0);
        f32x4 t0x = __builtin_amdgcn_mfma_f32_16x16x32_f16(aw[0][2], bx,  z, 0, 0, 0);
        f32x4 t10 = __builtin_amdgcn_mfma_f32_16x16x32_f16(aw[1][0], bh0, z, 0, 0, 0);
        f32x4 t11 = __builtin_amdgcn_mfma_f32_16x16x32_f16(aw[1][1], bh1, z, 0, 0, 0);
        f32x4 t1x = __builtin_amdgcn_mfma_f32_16x16x32_f16(aw[1][2], bx,  z, 0, 0, 0);
        f32x4 acc0 = (t00 + t01) + t0x;
        f32x4 acc1 = (t10 + t11) + t1x;

        // cell update: 2 cells/lane (units u = 8w+2q+p, batch col); packed b32 write
        _Float16* sw = &st[wb][0];
        {
            const float gi0 = acc0[0], gf0 = acc0[1], gg0 = acc0[2], go0 = acc0[3];
            const float gi1 = acc1[0], gf1 = acc1[1], gg1 = acc1[2], go1 = acc1[3];
            float c0 = sigm(gf0) * cst[0] + sigm(gi0) * tanh_f(gg0);
            float c1 = sigm(gf1) * cst[1] + sigm(gi1) * tanh_f(gg1);
            cst[0] = c0; cst[1] = c1;
            half2v hv;
            hv[0] = (_Float16)(sigm(go0) * tanh_f(c0));
            hv[1] = (_Float16)(sigm(go1) * tanh_f(c1));
            *(half2v*)&sw[col * S + 8 * w + 2 * q] = hv;
        }
        __syncthreads();
    }

    // ---- FC epilogue: final h in st[0] (TT even) ----
    if (tid < MB * 4) {
        const int b = tid >> 2, o = tid & 3;
        float s = b_fc[o];
        const float* wf = W_fc + o * HH;
        #pragma unroll
        for (int k = 0; k < HH; ++k)
            s = fmaf((float)st[0][b * S + k], wf[k], s);
        out[(size_t)(b0 + b) * 4 + o] = s;
    }
}

extern "C" void kernel_launch(void* const* d_in, const int* in_sizes, int n_in,
                              void* d_out, int out_size, void* d_ws, size_t ws_size,
                              hipStream_t stream) {
    const float* x    = (const float*)d_in[0];
    const float* W_ih = (const float*)d_in[1];
    const float* W_hh = (const float*)d_in[2];
    const float* b_ih = (const float*)d_in[3];
    const float* b_hh = (const float*)d_in[4];
    const float* W_fc = (const float*)d_in[5];
    const float* b_fc = (const float*)d_in[6];
    float* out = (float*)d_out;
    lstm_v6<<<2048 / MB, 512, 0, stream>>>(x, W_ih, W_hh, b_ih, b_hh, W_fc, b_fc, out);
}

// Round 8
// 277.289 us; speedup vs baseline: 1.3242x; 1.2036x over previous
//
#include <hip/hip_runtime.h>

typedef _Float16 half8 __attribute__((ext_vector_type(8)));
typedef _Float16 half4 __attribute__((ext_vector_type(4)));
typedef _Float16 half2v __attribute__((ext_vector_type(2)));
typedef float f32x4 __attribute__((ext_vector_type(4)));
typedef float f32x2 __attribute__((ext_vector_type(2)));

#define TT 512
#define HH 64
#define MB 8      // real batches per block -> 256 blocks (cols 8..15 garbage-contained)
#define S  104    // state row stride (f16): [h(64)|x(4)|1|zeros|pad]

__device__ __forceinline__ f32x2 exp2v(f32x2 v) {
    f32x2 r;
    r.x = __builtin_amdgcn_exp2f(v.x);
    r.y = __builtin_amdgcn_exp2f(v.y);
    return r;
}
__device__ __forceinline__ f32x2 rcpv(f32x2 v) {
    f32x2 r;
    r.x = __builtin_amdgcn_rcpf(v.x);
    r.y = __builtin_amdgcn_rcpf(v.y);
    return r;
}

__global__ __launch_bounds__(512, 1)
void lstm_v7(const float* __restrict__ x,
             const float* __restrict__ W_ih,
             const float* __restrict__ W_hh,
             const float* __restrict__ b_ih,
             const float* __restrict__ b_hh,
             const float* __restrict__ W_fc,
             const float* __restrict__ b_fc,
             float* __restrict__ out)
{
    __shared__ __align__(16) _Float16 st[2][16 * S];

    const int tid = threadIdx.x;
    const int w   = tid >> 6;      // wave 0..7
    const int l   = tid & 63;
    const int q   = l >> 4;
    const int col = l & 15;
    const int b0  = blockIdx.x * MB;

    // ---- persistent A fragments (weights), 2 tiles per wave ----
    // tile p of wave w covers gate-rows r(m) = 64*(m&3) + 8w + 2*(m>>2) + p
    // => lane (q,col) reg j = gate j of unit u = 8w + 2q + p
    half8 aw[2][3];
    #pragma unroll
    for (int p = 0; p < 2; ++p) {
        const int r = 64 * (col & 3) + 8 * w + 2 * (col >> 2) + p;
        #pragma unroll
        for (int c = 0; c < 2; ++c) {
            const float* src = W_hh + r * HH + 32 * c + 8 * q;
            half8 v;
            #pragma unroll
            for (int j = 0; j < 8; ++j) v[j] = (_Float16)src[j];
            aw[p][c] = v;
        }
        half8 v = {};
        if (q == 0) {   // k=64..67 -> W_ih, k=68 -> bias
            #pragma unroll
            for (int j = 0; j < 4; ++j) v[j] = (_Float16)W_ih[r * 4 + j];
            v[4] = (_Float16)(b_ih[r] + b_hh[r]);
        }
        aw[p][2] = v;
    }

    // ---- init LDS ----
    {
        _Float16* p0 = &st[0][0];
        for (int i = tid; i < 2 * 16 * S; i += 512) p0[i] = (_Float16)0.f;
    }
    __syncthreads();
    if (tid < 32) st[tid >> 4][(tid & 15) * S + 68] = (_Float16)1.0f;

    float4 xnext;
    if (tid < MB) {
        const float4* xb = (const float4*)(x + (size_t)(b0 + tid) * TT * 4);
        float4 x0 = xb[0];
        half4 hx;
        hx[0] = (_Float16)x0.x; hx[1] = (_Float16)x0.y;
        hx[2] = (_Float16)x0.z; hx[3] = (_Float16)x0.w;
        *(half4*)&st[0][tid * S + 64] = hx;
        xnext = xb[1];
    }
    __syncthreads();

    f32x2 cst = {0.f, 0.f};   // cells p=0,1 packed

    #pragma unroll 2
    for (int t = 0; t < TT; ++t) {
        const int rb = t & 1, wb = rb ^ 1;
        const _Float16* sr = &st[rb][0];

        half8 bh0 = *(const half8*)&sr[col * S +      8 * q];   // k 0..31
        half8 bh1 = *(const half8*)&sr[col * S + 32 + 8 * q];   // k 32..63
        half8 bx  = *(const half8*)&sr[col * S + 64];           // broadcast; q>0 -> A=0

        // write x_{t+1}; prefetch x_{t+2}
        if (tid < MB) {
            half4 hx;
            hx[0] = (_Float16)xnext.x; hx[1] = (_Float16)xnext.y;
            hx[2] = (_Float16)xnext.z; hx[3] = (_Float16)xnext.w;
            *(half4*)&st[wb][tid * S + 64] = hx;
            const int tn = (t + 2 < TT) ? (t + 2) : (TT - 1);
            xnext = *(const float4*)(x + ((size_t)(b0 + tid) * TT + tn) * 4);
        }

        // chained MFMA (x/bias chunk first), 2 independent tiles
        const f32x4 z = {0.f, 0.f, 0.f, 0.f};
        f32x4 acc0 = __builtin_amdgcn_mfma_f32_16x16x32_f16(aw[0][2], bx,  z,    0, 0, 0);
        f32x4 acc1 = __builtin_amdgcn_mfma_f32_16x16x32_f16(aw[1][2], bx,  z,    0, 0, 0);
        acc0 = __builtin_amdgcn_mfma_f32_16x16x32_f16(aw[0][0], bh0, acc0, 0, 0, 0);
        acc1 = __builtin_amdgcn_mfma_f32_16x16x32_f16(aw[1][0], bh0, acc1, 0, 0, 0);
        acc0 = __builtin_amdgcn_mfma_f32_16x16x32_f16(aw[0][1], bh1, acc0, 0, 0, 0);
        acc1 = __builtin_amdgcn_mfma_f32_16x16x32_f16(aw[1][1], bh1, acc1, 0, 0, 0);

        // ---- packed 2-cell update (units u = 8w+2q+p, batch col) ----
        // sig(a)         = rcp(1 + e2^(-1.4427 a))
        // sig(a)*tanh(b) = (E-1) * rcp((1 + e2^(-1.4427 a)) * (E+1)), E = e2^(2.8854 b)
        {
            const f32x2 gi = {acc0[0], acc1[0]};
            const f32x2 gf = {acc0[1], acc1[1]};
            const f32x2 gg = {acc0[2], acc1[2]};
            const f32x2 go = {acc0[3], acc1[3]};
            const float kN = -1.4426950408889634f, kP = 2.8853900817779268f;

            f32x2 EI = exp2v(kN * gi);
            f32x2 EF = exp2v(kN * gf);
            f32x2 EG = exp2v(kP * gg);
            f32x2 rF = rcpv(1.f + EF);
            f32x2 r1 = rcpv((1.f + EI) * (EG + 1.f));
            cst = cst * rF + (EG - 1.f) * r1;

            f32x2 EO = exp2v(kN * go);
            f32x2 EC = exp2v(kP * cst);
            f32x2 r2 = rcpv((1.f + EO) * (EC + 1.f));
            f32x2 hn = (EC - 1.f) * r2;

            half2v hv = __builtin_bit_cast(half2v,
                            __builtin_amdgcn_cvt_pkrtz(hn.x, hn.y));
            *(half2v*)&st[wb][col * S + 8 * w + 2 * q] = hv;   // 4B, 2-way banks: free
        }
        __syncthreads();
    }

    // ---- FC epilogue: final h in st[0] (TT even) ----
    if (tid < MB * 4) {
        const int b = tid >> 2, o = tid & 3;
        float s = b_fc[o];
        const float* wf = W_fc + o * HH;
        #pragma unroll
        for (int k = 0; k < HH; ++k)
            s = fmaf((float)st[0][b * S + k], wf[k], s);
        out[(size_t)(b0 + b) * 4 + o] = s;
    }
}

extern "C" void kernel_launch(void* const* d_in, const int* in_sizes, int n_in,
                              void* d_out, int out_size, void* d_ws, size_t ws_size,
                              hipStream_t stream) {
    const float* x    = (const float*)d_in[0];
    const float* W_ih = (const float*)d_in[1];
    const float* W_hh = (const float*)d_in[2];
    const float* b_ih = (const float*)d_in[3];
    const float* b_hh = (const float*)d_in[4];
    const float* W_fc = (const float*)d_in[5];
    const float* b_fc = (const float*)d_in[6];
    float* out = (float*)d_out;
    lstm_v7<<<2048 / MB, 512, 0, stream>>>(x, W_ih, W_hh, b_ih, b_hh, W_fc, b_fc, out);
}